// Round 6
// baseline (415.858 us; speedup 1.0000x reference)
//
#include <hip/hip_runtime.h>

// ---------------------------------------------------------------------------
// SelfAttention (B=8, C=512, T=4096, DK=64):
//   sigma = spectral norm of Wv (1 power iter); val = (Wv x)/sigma + bv
//   q = Wq x, k = Wk x; attn = softmax(q^T k / 8); out = val @ attn^T + x
// Pipeline:
//   sigma  -> inv_sigma
//   castw  -> Wc[640][512] bf16 = [Wq*log2e/8 ; Wk ; Wv/sigma]
//   castt  -> xT[b][t][c] bf16 (LDS transpose)
//   proj   -> unified MFMA GEMM: Q[t][d], K[t][d], V[c][t] (+bv)
//   flash  -> flash attention: swapped-QK softmax, shared-P phase-split PV,
//             asm-issued K/V fragment prefetch + counted vmcnt(8) waits,
//             ONE lgkmcnt-only barrier per tile, parity-buffered P
// ---------------------------------------------------------------------------

#define B_  8
#define C_  512
#define T_  4096
#define DK_ 64

typedef __bf16 bf16x8 __attribute__((ext_vector_type(8)));
typedef float  f32x4  __attribute__((ext_vector_type(4)));

static __device__ __forceinline__ unsigned short f2bf(float f) {
  unsigned u = __float_as_uint(f);
  u += 0x7fffu + ((u >> 16) & 1u);
  return (unsigned short)(u >> 16);
}

static __device__ __forceinline__ unsigned cvt_pk_bf16(float a, float b) {
  unsigned r;  // r.lo = bf16(a), r.hi = bf16(b), RNE
  asm("v_cvt_pk_bf16_f32 %0, %1, %2" : "=v"(r) : "v"(a), "v"(b));
  return r;
}

// raw barrier: LDS-visibility wait + barrier, NO vmcnt drain
#define BAR_LDS() asm volatile("s_waitcnt lgkmcnt(0)\ns_barrier" ::: "memory")
// counted VMEM wait: retire the 8 oldest outstanding loads; fence scheduling
#define WAIT_VM8() do { asm volatile("s_waitcnt vmcnt(8)" ::: "memory"); \
                        __builtin_amdgcn_sched_barrier(0); } while (0)

// ---------------------------------------------------------------------------
// Kernel 1: spectral norm -> inv_sigma
// ---------------------------------------------------------------------------
__global__ void sigma_kernel(const float* __restrict__ Wv,
                             const float* __restrict__ u,
                             float* __restrict__ sig) {
  __shared__ float red[512];
  __shared__ float vsh[512];
  __shared__ float snorm;
  int tid = threadIdx.x;  // 512 threads

  vsh[tid] = u[tid];
  __syncthreads();
  float acc = 0.f;
  for (int j = 0; j < 512; ++j) acc += Wv[(size_t)j * 512 + tid] * vsh[j];
  red[tid] = acc * acc;
  __syncthreads();
  for (int s = 256; s >= 1; s >>= 1) {
    if (tid < s) red[tid] += red[tid + s];
    __syncthreads();
  }
  if (tid == 0) snorm = sqrtf(red[0]) + 1e-12f;
  __syncthreads();
  float v = acc / snorm;
  __syncthreads();
  vsh[tid] = v;
  __syncthreads();
  float wacc = 0.f;
  for (int c = 0; c < 512; ++c) wacc += Wv[(size_t)tid * 512 + c] * vsh[c];
  red[tid] = wacc * wacc;
  __syncthreads();
  for (int s = 256; s >= 1; s >>= 1) {
    if (tid < s) red[tid] += red[tid + s];
    __syncthreads();
  }
  if (tid == 0) {
    float ww = red[0];
    float sigma = ww / (sqrtf(ww) + 1e-12f);
    sig[0] = 1.f / sigma;
  }
}

// ---------------------------------------------------------------------------
// Kernel 2: stack + scale weights to bf16: Wc[640][512]
// ---------------------------------------------------------------------------
__global__ __launch_bounds__(128)
void castw_kernel(const float* __restrict__ Wq, const float* __restrict__ Wk,
                  const float* __restrict__ Wv, const float* __restrict__ sig,
                  unsigned short* __restrict__ Wc) {
  int row = blockIdx.x;
  int c = threadIdx.x * 4;
  const float* src;
  float s;
  if (row < 64) {
    src = Wq + (size_t)row * 512;
    s = 1.4426950408889634f / 8.0f;
  } else if (row < 128) {
    src = Wk + (size_t)(row - 64) * 512;
    s = 1.0f;
  } else {
    src = Wv + (size_t)(row - 128) * 512;
    s = sig[0];
  }
  float4 v = *reinterpret_cast<const float4*>(src + c);
  ushort4 o;
  o.x = f2bf(v.x * s);
  o.y = f2bf(v.y * s);
  o.z = f2bf(v.z * s);
  o.w = f2bf(v.w * s);
  *reinterpret_cast<ushort4*>(Wc + (size_t)row * 512 + c) = o;
}

// ---------------------------------------------------------------------------
// Kernel 3: transpose-cast x[b][c][t] f32 -> xT[b][t][c] bf16.
// ---------------------------------------------------------------------------
__global__ __launch_bounds__(256)
void castt_kernel(const float* __restrict__ x, unsigned short* __restrict__ xT) {
  __shared__ __align__(16) unsigned short ldsT[64][72];  // [t][c], +8 pad
  int tid = threadIdx.x;
  int t0 = blockIdx.x * 64, c0 = blockIdx.y * 64, b = blockIdx.z;
  const float* xb = x + ((size_t)b * C_ + c0) * T_ + t0;
#pragma unroll
  for (int k2 = 0; k2 < 4; ++k2) {
    int idx = k2 * 256 + tid;
    int c = idx >> 4, t4 = (idx & 15) * 4;
    float4 v = *reinterpret_cast<const float4*>(xb + (size_t)c * T_ + t4);
    ldsT[t4 + 0][c] = f2bf(v.x);
    ldsT[t4 + 1][c] = f2bf(v.y);
    ldsT[t4 + 2][c] = f2bf(v.z);
    ldsT[t4 + 3][c] = f2bf(v.w);
  }
  __syncthreads();
  unsigned short* xTb = xT + ((size_t)b * T_ + t0) * C_ + c0;
#pragma unroll
  for (int k2 = 0; k2 < 2; ++k2) {
    int idx = k2 * 256 + tid;
    int t = idx >> 3, ch = idx & 7;
    bf16x8 v = *reinterpret_cast<const bf16x8*>(&ldsT[t][ch * 8]);
    *reinterpret_cast<bf16x8*>(xTb + (size_t)t * C_ + ch * 8) = v;
  }
}

// ---------------------------------------------------------------------------
// Kernel 4: unified projection GEMM (bf16 MFMA).  (unchanged, verified)
// ---------------------------------------------------------------------------
__global__ __launch_bounds__(512, 2)
void proj_kernel(const unsigned short* __restrict__ Wc,
                 const unsigned short* __restrict__ xT,
                 const float* __restrict__ bv,
                 unsigned short* __restrict__ Q,
                 unsigned short* __restrict__ Kk,
                 unsigned short* __restrict__ V) {
  __shared__ __align__(16) char smem[98304];  // 96KB: x 2x8KB | W 2x40KB
  const int tid = threadIdx.x;
  const int w = tid >> 6;
  const int lane = tid & 63;
  const int col = lane & 15;
  const int g = lane >> 4;
  const int b = blockIdx.x & 7;
  const int t0 = (blockIdx.x >> 3) * 128;

  const unsigned short* xTb = xT + ((size_t)b * T_ + t0) * C_;

  auto stageX = [&](int bsel, int kc) {
    int off = w * 1024 + lane * 16;
    int tl = off >> 6;
    int cb = off & 63;
    const unsigned short* src = xTb + (size_t)tl * C_ + kc + cb / 2;
    __builtin_amdgcn_global_load_lds(
        (const __attribute__((address_space(1))) unsigned int*)src,
        (__attribute__((address_space(3))) unsigned int*)(smem + bsel * 8192 + off),
        16, 0, 0);
  };
  auto stageW = [&](int bsel, int kc) {
#pragma unroll
    for (int i = 0; i < 5; ++i) {
      int off = i * 8192 + w * 1024 + lane * 16;
      int o = off >> 6;
      int cb = off & 63;
      const unsigned short* src = Wc + (size_t)o * 512 + kc + cb / 2;
      __builtin_amdgcn_global_load_lds(
          (const __attribute__((address_space(1))) unsigned int*)src,
          (__attribute__((address_space(3))) unsigned int*)(smem + 16384 + bsel * 40960 + off),
          16, 0, 0);
    }
  };

  f32x4 acc[5][8];
#pragma unroll
  for (int of = 0; of < 5; ++of)
#pragma unroll
    for (int j = 0; j < 8; ++j) acc[of][j] = (f32x4){0.f, 0.f, 0.f, 0.f};

  stageX(0, 0);
  stageW(0, 0);
  __syncthreads();
  int cur = 0;

  for (int ks = 0; ks < 16; ++ks) {
    int kc = ks * 32;
    if (ks < 15) {
      stageX(cur ^ 1, kc + 32);
      stageW(cur ^ 1, kc + 32);
    }
    bf16x8 af[5], bfr[8];
#pragma unroll
    for (int of = 0; of < 5; ++of) {
      int o = w * 80 + of * 16 + col;
      af[of] = *reinterpret_cast<const bf16x8*>(smem + 16384 + cur * 40960 + o * 64 + g * 16);
    }
#pragma unroll
    for (int j = 0; j < 8; ++j) {
      int tl = 16 * j + col;
      bfr[j] = *reinterpret_cast<const bf16x8*>(smem + cur * 8192 + tl * 64 + g * 16);
    }
#pragma unroll
    for (int of = 0; of < 5; ++of)
#pragma unroll
      for (int j = 0; j < 8; ++j)
        acc[of][j] = __builtin_amdgcn_mfma_f32_16x16x32_bf16(af[of], bfr[j], acc[of][j], 0, 0, 0);
    __syncthreads();
    cur ^= 1;
  }

  unsigned short* qkt = (unsigned short*)smem;                       // [128][136]
  unsigned short* vt = (unsigned short*)(smem + 34816 + w * 4352);   // [16][136]/wave
  unsigned short* Vb = V + (size_t)b * C_ * T_;

#pragma unroll
  for (int of = 0; of < 5; ++of) {
    int o0 = w * 80 + of * 16;
    if (o0 < 128) {
#pragma unroll
      for (int j = 0; j < 8; ++j)
#pragma unroll
        for (int r = 0; r < 4; ++r)
          qkt[(16 * j + col) * 136 + o0 + g * 4 + r] = f2bf(acc[of][j][r]);
    } else {
      int c0 = o0 - 128;
      float bvr[4];
#pragma unroll
      for (int r = 0; r < 4; ++r) bvr[r] = bv[c0 + g * 4 + r];
#pragma unroll
      for (int j = 0; j < 8; ++j)
#pragma unroll
        for (int r = 0; r < 4; ++r)
          vt[(g * 4 + r) * 136 + 16 * j + col] = f2bf(acc[of][j][r] + bvr[r]);
#pragma unroll
      for (int p = 0; p < 4; ++p) {
        int o_r = p * 4 + g;
        bf16x8 v8 = *reinterpret_cast<const bf16x8*>((char*)vt + o_r * 272 + col * 16);
        *reinterpret_cast<bf16x8*>(Vb + (size_t)(c0 + o_r) * T_ + t0 + col * 8) = v8;
      }
    }
  }
  __syncthreads();
  unsigned short* Qb = Q + (size_t)b * T_ * DK_;
  unsigned short* Kb = Kk + (size_t)b * T_ * DK_;
#pragma unroll
  for (int k2 = 0; k2 < 2; ++k2) {
    int idx = k2 * 512 + tid;
    int t = idx >> 3, ch = idx & 7;
    bf16x8 q8 = *reinterpret_cast<const bf16x8*>(&qkt[t * 136 + ch * 8]);
    *reinterpret_cast<bf16x8*>(Qb + (size_t)(t0 + t) * DK_ + ch * 8) = q8;
    bf16x8 k8 = *reinterpret_cast<const bf16x8*>(&qkt[t * 136 + 64 + ch * 8]);
    *reinterpret_cast<bf16x8*>(Kb + (size_t)(t0 + t) * DK_ + ch * 8) = k8;
  }
}

// ---------------------------------------------------------------------------
// Kernel 5: flash attention + residual.
// grid 256 blocks (1/CU): b = bid&7 (XCD-pinned), t0 = (bid>>3)*128.
// 512 threads = 8 waves.  Per 64-s tile:
//   WAIT_VM8 (K(i) ready; V(i) still in flight)
//   QK^T (8 MFMA, S^T = mfma(K,Q)) ; issue K(i+1) [asm, 8 loads]
//   softmax (lane-local rows, 2+2 shfl), defer-rescale, P -> p_lds[par]
//   BAR (lgkmcnt only)
//   WAIT_VM8 (V(i) ready; K(i+1) in flight)
//   rescale (rare) ; PV (64 MFMA, setprio) ; issue V(i+1) [asm, 8 loads]
// K/V fragment loads are volatile asm global_load_dwordx4 -> compiler cannot
// sink them to use sites (R5 bug: sunk prefetch = exposed L2 latency/iter).
// ---------------------------------------------------------------------------
__global__ __launch_bounds__(512, 2)
void flash_kernel(const unsigned short* __restrict__ Q,
                  const unsigned short* __restrict__ Kk,
                  const unsigned short* __restrict__ V,
                  const float* __restrict__ x, float* __restrict__ out) {
  __shared__ __align__(16) unsigned short p_lds[2][128 * 64];  // 2 x 16KB
  __shared__ __align__(16) float scale_lds[2][8][16];
  __shared__ __align__(16) float l_lds[128];
  __shared__ unsigned long long flags_lds[2];

  const int tid = threadIdx.x;
  const int w = tid >> 6;
  const int lane = tid & 63;
  const int col = lane & 15;
  const int g = lane >> 4;
  const int b = blockIdx.x & 7;            // batch == XCD slot
  const int t0 = (blockIdx.x >> 3) * 128;
  const int trow0 = t0 + w * 16;

  const unsigned short* Qb = Q + (size_t)b * T_ * DK_;
  const unsigned short* Kb = Kk + (size_t)b * T_ * DK_;
  const unsigned short* Vb = V + (size_t)b * C_ * T_;

  // Q B-fragments (col = q row); pin so the compiler's vmcnt for these
  // lands HERE, not inside the loop.
  bf16x8 qf0, qf1;
  {
    const unsigned short* qrow = Qb + (size_t)(trow0 + col) * DK_ + g * 8;
    qf0 = *reinterpret_cast<const bf16x8*>(qrow);
    qf1 = *reinterpret_cast<const bf16x8*>(qrow + 32);
    asm volatile("" : "+v"(qf0), "+v"(qf1));
  }

  // K fragment bases: row = s0+col+16j, byte = (s0+col)*128 + 2048j + 64ks + 16g
  const char* ka = (const char*)Kb + (size_t)col * 128 + g * 16;        // j=0,1
  const char* kb2 = ka + 4096;                                          // j=2,3
  // V fragment bases: c = 64w+16ct+col, byte = c*8192 + 2*s0 + 64ks + 16g
  const char* va0 = (const char*)Vb + (size_t)(64 * w + col) * 8192 + g * 16;
  const char* va1 = va0 + 16 * 8192;
  const char* va2 = va0 + 32 * 8192;
  const char* va3 = va0 + 48 * 8192;

  bf16x8 k00, k10, k01, k11, k02, k12, k03, k13;   // kf[ks][j]
  bf16x8 v00, v10, v01, v11, v02, v12, v03, v13;   // vf[ks][ct]

#define ISSUE_K()                                                          \
  asm volatile(                                                            \
      "global_load_dwordx4 %0, %8, off\n\t"                                \
      "global_load_dwordx4 %1, %8, off offset:64\n\t"                      \
      "global_load_dwordx4 %2, %8, off offset:2048\n\t"                    \
      "global_load_dwordx4 %3, %8, off offset:2112\n\t"                    \
      "global_load_dwordx4 %4, %9, off\n\t"                                \
      "global_load_dwordx4 %5, %9, off offset:64\n\t"                      \
      "global_load_dwordx4 %6, %9, off offset:2048\n\t"                    \
      "global_load_dwordx4 %7, %9, off offset:2112\n\t"                    \
      : "=&v"(k00), "=&v"(k10), "=&v"(k01), "=&v"(k11),                    \
        "=&v"(k02), "=&v"(k12), "=&v"(k03), "=&v"(k13)                     \
      : "v"(ka), "v"(kb2))

#define ISSUE_V()                                                          \
  asm volatile(                                                            \
      "global_load_dwordx4 %0, %8, off\n\t"                                \
      "global_load_dwordx4 %1, %8, off offset:64\n\t"                      \
      "global_load_dwordx4 %2, %9, off\n\t"                                \
      "global_load_dwordx4 %3, %9, off offset:64\n\t"                      \
      "global_load_dwordx4 %4, %10, off\n\t"                               \
      "global_load_dwordx4 %5, %10, off offset:64\n\t"                     \
      "global_load_dwordx4 %6, %11, off\n\t"                               \
      "global_load_dwordx4 %7, %11, off offset:64\n\t"                     \
      : "=&v"(v00), "=&v"(v10), "=&v"(v01), "=&v"(v11),                    \
        "=&v"(v02), "=&v"(v12), "=&v"(v03), "=&v"(v13)                     \
      : "v"(va0), "v"(va1), "v"(va2), "v"(va3))

  float m_run = -1e30f, l_run = 0.f;
  f32x4 o_acc[8][4];
#pragma unroll
  for (int qt = 0; qt < 8; ++qt)
#pragma unroll
    for (int ct = 0; ct < 4; ++ct) o_acc[qt][ct] = (f32x4){0.f, 0.f, 0.f, 0.f};

  ISSUE_K();  // K(0)  [oldest]
  ISSUE_V();  // V(0)

  const float RTHR = 10.0f;  // defer-rescale threshold (log2 domain)
  const int prow = w * 16 + col;           // this lane's q row in p_lds
  const int pswz = (prow & 7) << 4;

  for (int it = 0; it < T_ / 64; ++it) {
    const int par = it & 1;
    char* pbase = (char*)p_lds + par * 16384;

    WAIT_VM8();  // K(i) resident (V(i) may still be in flight)

    // ---- S^T = K Q^T (8 MFMA); lane (col=q) holds s = 16j+4g+r ----
    f32x4 sacc[4];
#pragma unroll
    for (int j = 0; j < 4; ++j) sacc[j] = (f32x4){0.f, 0.f, 0.f, 0.f};
    sacc[0] = __builtin_amdgcn_mfma_f32_16x16x32_bf16(k00, qf0, sacc[0], 0, 0, 0);
    sacc[1] = __builtin_amdgcn_mfma_f32_16x16x32_bf16(k01, qf0, sacc[1], 0, 0, 0);
    sacc[2] = __builtin_amdgcn_mfma_f32_16x16x32_bf16(k02, qf0, sacc[2], 0, 0, 0);
    sacc[3] = __builtin_amdgcn_mfma_f32_16x16x32_bf16(k03, qf0, sacc[3], 0, 0, 0);
    sacc[0] = __builtin_amdgcn_mfma_f32_16x16x32_bf16(k10, qf1, sacc[0], 0, 0, 0);
    sacc[1] = __builtin_amdgcn_mfma_f32_16x16x32_bf16(k11, qf1, sacc[1], 0, 0, 0);
    sacc[2] = __builtin_amdgcn_mfma_f32_16x16x32_bf16(k12, qf1, sacc[2], 0, 0, 0);
    sacc[3] = __builtin_amdgcn_mfma_f32_16x16x32_bf16(k13, qf1, sacc[3], 0, 0, 0);

    // kf consumed -> issue K(i+1) (overrun on last iter reads valid ws mem)
    ka += 8192;
    kb2 += 8192;
    ISSUE_K();

    // ---- per-row max + defer-rescale ----
    float u0 = fmaxf(fmaxf(sacc[0][0], sacc[0][1]), sacc[0][2]);
    float u1 = fmaxf(fmaxf(sacc[0][3], sacc[1][0]), sacc[1][1]);
    float u2 = fmaxf(fmaxf(sacc[1][2], sacc[1][3]), sacc[2][0]);
    float u3 = fmaxf(fmaxf(sacc[2][1], sacc[2][2]), sacc[2][3]);
    float u4 = fmaxf(fmaxf(sacc[3][0], sacc[3][1]), sacc[3][2]);
    float tm = fmaxf(fmaxf(fmaxf(u0, u1), fmaxf(u2, u3)), fmaxf(u4, sacc[3][3]));
    tm = fmaxf(tm, __shfl_xor(tm, 16));
    tm = fmaxf(tm, __shfl_xor(tm, 32));

    int wave_any = __any(tm > m_run + RTHR);
    float sc = 1.0f;
    if (wave_any) {
      float m_new = fmaxf(m_run, tm);
      sc = __builtin_amdgcn_exp2f(m_run - m_new);
      m_run = m_new;
      if (lane < 16) scale_lds[par][w][lane] = sc;
    }
    if (lane == 0)
      ((volatile unsigned char*)&flags_lds[par])[w] = (unsigned char)wave_any;

    // ---- P = exp2(S - m), cvt_pk pack, 4x ds_write_b64; l update ----
    float rs = 0.f;
    char* prow_base = pbase + prow * 128;
#pragma unroll
    for (int j = 0; j < 4; ++j) {
      float p0 = __builtin_amdgcn_exp2f(sacc[j][0] - m_run);
      float p1 = __builtin_amdgcn_exp2f(sacc[j][1] - m_run);
      float p2 = __builtin_amdgcn_exp2f(sacc[j][2] - m_run);
      float p3 = __builtin_amdgcn_exp2f(sacc[j][3] - m_run);
      rs += (p0 + p1) + (p2 + p3);
      uint2 pk2 = {cvt_pk_bf16(p0, p1), cvt_pk_bf16(p2, p3)};
      *reinterpret_cast<uint2*>(prow_base + (((16 * j + 4 * g) * 2) ^ pswz)) = pk2;
    }
    rs += __shfl_xor(rs, 16);
    rs += __shfl_xor(rs, 32);
    l_run = l_run * sc + rs;

    BAR_LDS();  // P/scales/flags[par] visible; prev parity free

    WAIT_VM8();  // V(i) resident (K(i+1) still in flight)

    // ---- o_acc rescale (rare; wave-uniform per qt) ----
    unsigned long long fl = flags_lds[par];
    if (fl) {
#pragma unroll
      for (int qt = 0; qt < 8; ++qt)
        if ((fl >> (8 * qt)) & 0xffull) {
          f32x4 s4 = *reinterpret_cast<const f32x4*>(&scale_lds[par][qt][4 * g]);
#pragma unroll
          for (int ct = 0; ct < 4; ++ct) o_acc[qt][ct] *= s4;
        }
    }

    // ---- PV: o_acc[qt][ct] += P[16qt..+16] x V[64w+16ct..+16] ----
    __builtin_amdgcn_s_setprio(1);
#pragma unroll
    for (int qt = 0; qt < 8; ++qt) {
      int row = 16 * qt + col;
      const char* pr = pbase + row * 128;
      int swz = (row & 7) << 4;
      bf16x8 pa0 = *reinterpret_cast<const bf16x8*>(pr + ((16 * g) ^ swz));
      bf16x8 pa1 = *reinterpret_cast<const bf16x8*>(pr + ((64 + 16 * g) ^ swz));
      o_acc[qt][0] = __builtin_amdgcn_mfma_f32_16x16x32_bf16(pa0, v00, o_acc[qt][0], 0, 0, 0);
      o_acc[qt][1] = __builtin_amdgcn_mfma_f32_16x16x32_bf16(pa0, v01, o_acc[qt][1], 0, 0, 0);
      o_acc[qt][2] = __builtin_amdgcn_mfma_f32_16x16x32_bf16(pa0, v02, o_acc[qt][2], 0, 0, 0);
      o_acc[qt][3] = __builtin_amdgcn_mfma_f32_16x16x32_bf16(pa0, v03, o_acc[qt][3], 0, 0, 0);
      o_acc[qt][0] = __builtin_amdgcn_mfma_f32_16x16x32_bf16(pa1, v10, o_acc[qt][0], 0, 0, 0);
      o_acc[qt][1] = __builtin_amdgcn_mfma_f32_16x16x32_bf16(pa1, v11, o_acc[qt][1], 0, 0, 0);
      o_acc[qt][2] = __builtin_amdgcn_mfma_f32_16x16x32_bf16(pa1, v12, o_acc[qt][2], 0, 0, 0);
      o_acc[qt][3] = __builtin_amdgcn_mfma_f32_16x16x32_bf16(pa1, v13, o_acc[qt][3], 0, 0, 0);
    }
    __builtin_amdgcn_s_setprio(0);

    // vf consumed -> issue V(i+1)
    va0 += 128;
    va1 += 128;
    va2 += 128;
    va3 += 128;
    ISSUE_V();
  }

  asm volatile("s_waitcnt vmcnt(0)" ::: "memory");  // drain overrun prefetch

  // ---- epilogue: share l, direct coalesced f32x4 stores + residual ----
  if (lane < 16) l_lds[w * 16 + lane] = l_run;
  BAR_LDS();

  const float* xb = x + (size_t)b * C_ * T_;
  float* ob = out + (size_t)b * C_ * T_;
#pragma unroll
  for (int qt = 0; qt < 8; ++qt) {
    f32x4 l4 = *reinterpret_cast<const f32x4*>(&l_lds[16 * qt + 4 * g]);
    f32x4 linv;
#pragma unroll
    for (int r = 0; r < 4; ++r) linv[r] = 1.f / l4[r];
#pragma unroll
    for (int ct = 0; ct < 4; ++ct) {
      size_t idx = (size_t)(64 * w + 16 * ct + col) * T_ + t0 + 16 * qt + 4 * g;
      f32x4 xv = *reinterpret_cast<const f32x4*>(xb + idx);
      f32x4 o = o_acc[qt][ct];
#pragma unroll
      for (int r = 0; r < 4; ++r) o[r] = o[r] * linv[r] + xv[r];
      *reinterpret_cast<f32x4*>(ob + idx) = o;
    }
  }
#undef ISSUE_K
#undef ISSUE_V
}

// ---------------------------------------------------------------------------
extern "C" void kernel_launch(void* const* d_in, const int* in_sizes, int n_in,
                              void* d_out, int out_size, void* d_ws, size_t ws_size,
                              hipStream_t stream) {
  const float* x  = (const float*)d_in[0];
  const float* Wq = (const float*)d_in[1];
  const float* Wk = (const float*)d_in[2];
  const float* Wv = (const float*)d_in[3];
  const float* bv = (const float*)d_in[4];
  const float* u  = (const float*)d_in[5];
  float* out = (float*)d_out;

  char* ws = (char*)d_ws;
  float* sig = (float*)ws;
  unsigned short* Q  = (unsigned short*)(ws + 1024);
  unsigned short* Kk = (unsigned short*)(ws + 1024 + (size_t)4 * 1024 * 1024);
  unsigned short* V  = (unsigned short*)(ws + 1024 + (size_t)8 * 1024 * 1024);
  unsigned short* xT = (unsigned short*)(ws + 1024 + (size_t)40 * 1024 * 1024);
  unsigned short* Wc = (unsigned short*)(ws + 1024 + (size_t)72 * 1024 * 1024);

  sigma_kernel<<<1, 512, 0, stream>>>(Wv, u, sig);
  castw_kernel<<<640, 128, 0, stream>>>(Wq, Wk, Wv, sig, Wc);
  castt_kernel<<<dim3(T_ / 64, C_ / 64, B_), 256, 0, stream>>>(x, xT);
  proj_kernel<<<256, 512, 0, stream>>>(Wc, xT, bv, Q, Kk, V);
  flash_kernel<<<256, 512, 0, stream>>>(Q, Kk, V, x, out);
}

// Round 8
// 396.409 us; speedup vs baseline: 1.0491x; 1.0491x over previous
//
#include <hip/hip_runtime.h>

// ---------------------------------------------------------------------------
// SelfAttention (B=8, C=512, T=4096, DK=64):
//   sigma = spectral norm of Wv (1 power iter); val = (Wv x)/sigma + bv
//   q = Wq x, k = Wk x; attn = softmax(q^T k / 8); out = val @ attn^T + x
// Pipeline:
//   sigma  -> inv_sigma
//   castw  -> Wc[640][512] bf16 = [Wq*log2e/8 ; Wk ; Wv/sigma]
//   castt  -> xT[b][t][c] bf16 (LDS transpose)
//   proj   -> unified MFMA GEMM: Q[t][d], K[t][d], V[c][t] (+bv)
//   flash  -> flash attention: 4-wave blocks (64q x 256ch), 2 blocks/CU,
//             K tile in LDS (DMA, parity), V in regs issued intra-iter,
//             ONE vmcnt(0)+lgkm barrier per tile (spill-robust), swapped-QK
//             softmax, shared-P PV
// ---------------------------------------------------------------------------

#define B_  8
#define C_  512
#define T_  4096
#define DK_ 64

typedef __bf16 bf16x8 __attribute__((ext_vector_type(8)));
typedef float  f32x4  __attribute__((ext_vector_type(4)));

static __device__ __forceinline__ unsigned short f2bf(float f) {
  unsigned u = __float_as_uint(f);
  u += 0x7fffu + ((u >> 16) & 1u);
  return (unsigned short)(u >> 16);
}

static __device__ __forceinline__ unsigned cvt_pk_bf16(float a, float b) {
  unsigned r;  // r.lo = bf16(a), r.hi = bf16(b), RNE
  asm("v_cvt_pk_bf16_f32 %0, %1, %2" : "=v"(r) : "v"(a), "v"(b));
  return r;
}

static __device__ __forceinline__ unsigned long long rfl64(const void* p) {
  unsigned long long a = (unsigned long long)p;
  unsigned lo = __builtin_amdgcn_readfirstlane((unsigned)a);
  unsigned hi = __builtin_amdgcn_readfirstlane((unsigned)(a >> 32));
  return ((unsigned long long)hi << 32) | lo;
}

// raw barrier: LDS-visibility wait + barrier
#define BAR_LDS() asm volatile("s_waitcnt lgkmcnt(0)\ns_barrier" ::: "memory")
// full VMEM drain + scheduling fence (robust to compiler-inserted scratch ops)
#define WAIT_VM0() do { asm volatile("s_waitcnt vmcnt(0)" ::: "memory"); \
                        __builtin_amdgcn_sched_barrier(0); } while (0)

// ---------------------------------------------------------------------------
// Kernel 1: spectral norm -> inv_sigma
// ---------------------------------------------------------------------------
__global__ void sigma_kernel(const float* __restrict__ Wv,
                             const float* __restrict__ u,
                             float* __restrict__ sig) {
  __shared__ float red[512];
  __shared__ float vsh[512];
  __shared__ float snorm;
  int tid = threadIdx.x;  // 512 threads

  vsh[tid] = u[tid];
  __syncthreads();
  float acc = 0.f;
  for (int j = 0; j < 512; ++j) acc += Wv[(size_t)j * 512 + tid] * vsh[j];
  red[tid] = acc * acc;
  __syncthreads();
  for (int s = 256; s >= 1; s >>= 1) {
    if (tid < s) red[tid] += red[tid + s];
    __syncthreads();
  }
  if (tid == 0) snorm = sqrtf(red[0]) + 1e-12f;
  __syncthreads();
  float v = acc / snorm;
  __syncthreads();
  vsh[tid] = v;
  __syncthreads();
  float wacc = 0.f;
  for (int c = 0; c < 512; ++c) wacc += Wv[(size_t)tid * 512 + c] * vsh[c];
  red[tid] = wacc * wacc;
  __syncthreads();
  for (int s = 256; s >= 1; s >>= 1) {
    if (tid < s) red[tid] += red[tid + s];
    __syncthreads();
  }
  if (tid == 0) {
    float ww = red[0];
    float sigma = ww / (sqrtf(ww) + 1e-12f);
    sig[0] = 1.f / sigma;
  }
}

// ---------------------------------------------------------------------------
// Kernel 2: stack + scale weights to bf16: Wc[640][512]
// ---------------------------------------------------------------------------
__global__ __launch_bounds__(128)
void castw_kernel(const float* __restrict__ Wq, const float* __restrict__ Wk,
                  const float* __restrict__ Wv, const float* __restrict__ sig,
                  unsigned short* __restrict__ Wc) {
  int row = blockIdx.x;
  int c = threadIdx.x * 4;
  const float* src;
  float s;
  if (row < 64) {
    src = Wq + (size_t)row * 512;
    s = 1.4426950408889634f / 8.0f;
  } else if (row < 128) {
    src = Wk + (size_t)(row - 64) * 512;
    s = 1.0f;
  } else {
    src = Wv + (size_t)(row - 128) * 512;
    s = sig[0];
  }
  float4 v = *reinterpret_cast<const float4*>(src + c);
  ushort4 o;
  o.x = f2bf(v.x * s);
  o.y = f2bf(v.y * s);
  o.z = f2bf(v.z * s);
  o.w = f2bf(v.w * s);
  *reinterpret_cast<ushort4*>(Wc + (size_t)row * 512 + c) = o;
}

// ---------------------------------------------------------------------------
// Kernel 3: transpose-cast x[b][c][t] f32 -> xT[b][t][c] bf16.
// ---------------------------------------------------------------------------
__global__ __launch_bounds__(256)
void castt_kernel(const float* __restrict__ x, unsigned short* __restrict__ xT) {
  __shared__ __align__(16) unsigned short ldsT[64][72];  // [t][c], +8 pad
  int tid = threadIdx.x;
  int t0 = blockIdx.x * 64, c0 = blockIdx.y * 64, b = blockIdx.z;
  const float* xb = x + ((size_t)b * C_ + c0) * T_ + t0;
#pragma unroll
  for (int k2 = 0; k2 < 4; ++k2) {
    int idx = k2 * 256 + tid;
    int c = idx >> 4, t4 = (idx & 15) * 4;
    float4 v = *reinterpret_cast<const float4*>(xb + (size_t)c * T_ + t4);
    ldsT[t4 + 0][c] = f2bf(v.x);
    ldsT[t4 + 1][c] = f2bf(v.y);
    ldsT[t4 + 2][c] = f2bf(v.z);
    ldsT[t4 + 3][c] = f2bf(v.w);
  }
  __syncthreads();
  unsigned short* xTb = xT + ((size_t)b * T_ + t0) * C_ + c0;
#pragma unroll
  for (int k2 = 0; k2 < 2; ++k2) {
    int idx = k2 * 256 + tid;
    int t = idx >> 3, ch = idx & 7;
    bf16x8 v = *reinterpret_cast<const bf16x8*>(&ldsT[t][ch * 8]);
    *reinterpret_cast<bf16x8*>(xTb + (size_t)t * C_ + ch * 8) = v;
  }
}

// ---------------------------------------------------------------------------
// Kernel 4: unified projection GEMM (bf16 MFMA).  (unchanged, verified)
// ---------------------------------------------------------------------------
__global__ __launch_bounds__(512, 2)
void proj_kernel(const unsigned short* __restrict__ Wc,
                 const unsigned short* __restrict__ xT,
                 const float* __restrict__ bv,
                 unsigned short* __restrict__ Q,
                 unsigned short* __restrict__ Kk,
                 unsigned short* __restrict__ V) {
  __shared__ __align__(16) char smem[98304];  // 96KB: x 2x8KB | W 2x40KB
  const int tid = threadIdx.x;
  const int w = tid >> 6;
  const int lane = tid & 63;
  const int col = lane & 15;
  const int g = lane >> 4;
  const int b = blockIdx.x & 7;
  const int t0 = (blockIdx.x >> 3) * 128;

  const unsigned short* xTb = xT + ((size_t)b * T_ + t0) * C_;

  auto stageX = [&](int bsel, int kc) {
    int off = w * 1024 + lane * 16;
    int tl = off >> 6;
    int cb = off & 63;
    const unsigned short* src = xTb + (size_t)tl * C_ + kc + cb / 2;
    __builtin_amdgcn_global_load_lds(
        (const __attribute__((address_space(1))) unsigned int*)src,
        (__attribute__((address_space(3))) unsigned int*)(smem + bsel * 8192 + off),
        16, 0, 0);
  };
  auto stageW = [&](int bsel, int kc) {
#pragma unroll
    for (int i = 0; i < 5; ++i) {
      int off = i * 8192 + w * 1024 + lane * 16;
      int o = off >> 6;
      int cb = off & 63;
      const unsigned short* src = Wc + (size_t)o * 512 + kc + cb / 2;
      __builtin_amdgcn_global_load_lds(
          (const __attribute__((address_space(1))) unsigned int*)src,
          (__attribute__((address_space(3))) unsigned int*)(smem + 16384 + bsel * 40960 + off),
          16, 0, 0);
    }
  };

  f32x4 acc[5][8];
#pragma unroll
  for (int of = 0; of < 5; ++of)
#pragma unroll
    for (int j = 0; j < 8; ++j) acc[of][j] = (f32x4){0.f, 0.f, 0.f, 0.f};

  stageX(0, 0);
  stageW(0, 0);
  __syncthreads();
  int cur = 0;

  for (int ks = 0; ks < 16; ++ks) {
    int kc = ks * 32;
    if (ks < 15) {
      stageX(cur ^ 1, kc + 32);
      stageW(cur ^ 1, kc + 32);
    }
    bf16x8 af[5], bfr[8];
#pragma unroll
    for (int of = 0; of < 5; ++of) {
      int o = w * 80 + of * 16 + col;
      af[of] = *reinterpret_cast<const bf16x8*>(smem + 16384 + cur * 40960 + o * 64 + g * 16);
    }
#pragma unroll
    for (int j = 0; j < 8; ++j) {
      int tl = 16 * j + col;
      bfr[j] = *reinterpret_cast<const bf16x8*>(smem + cur * 8192 + tl * 64 + g * 16);
    }
#pragma unroll
    for (int of = 0; of < 5; ++of)
#pragma unroll
      for (int j = 0; j < 8; ++j)
        acc[of][j] = __builtin_amdgcn_mfma_f32_16x16x32_bf16(af[of], bfr[j], acc[of][j], 0, 0, 0);
    __syncthreads();
    cur ^= 1;
  }

  unsigned short* qkt = (unsigned short*)smem;                       // [128][136]
  unsigned short* vt = (unsigned short*)(smem + 34816 + w * 4352);   // [16][136]/wave
  unsigned short* Vb = V + (size_t)b * C_ * T_;

#pragma unroll
  for (int of = 0; of < 5; ++of) {
    int o0 = w * 80 + of * 16;
    if (o0 < 128) {
#pragma unroll
      for (int j = 0; j < 8; ++j)
#pragma unroll
        for (int r = 0; r < 4; ++r)
          qkt[(16 * j + col) * 136 + o0 + g * 4 + r] = f2bf(acc[of][j][r]);
    } else {
      int c0 = o0 - 128;
      float bvr[4];
#pragma unroll
      for (int r = 0; r < 4; ++r) bvr[r] = bv[c0 + g * 4 + r];
#pragma unroll
      for (int j = 0; j < 8; ++j)
#pragma unroll
        for (int r = 0; r < 4; ++r)
          vt[(g * 4 + r) * 136 + 16 * j + col] = f2bf(acc[of][j][r] + bvr[r]);
#pragma unroll
      for (int p = 0; p < 4; ++p) {
        int o_r = p * 4 + g;
        bf16x8 v8 = *reinterpret_cast<const bf16x8*>((char*)vt + o_r * 272 + col * 16);
        *reinterpret_cast<bf16x8*>(Vb + (size_t)(c0 + o_r) * T_ + t0 + col * 8) = v8;
      }
    }
  }
  __syncthreads();
  unsigned short* Qb = Q + (size_t)b * T_ * DK_;
  unsigned short* Kb = Kk + (size_t)b * T_ * DK_;
#pragma unroll
  for (int k2 = 0; k2 < 2; ++k2) {
    int idx = k2 * 512 + tid;
    int t = idx >> 3, ch = idx & 7;
    bf16x8 q8 = *reinterpret_cast<const bf16x8*>(&qkt[t * 136 + ch * 8]);
    *reinterpret_cast<bf16x8*>(Qb + (size_t)(t0 + t) * DK_ + ch * 8) = q8;
    bf16x8 k8 = *reinterpret_cast<const bf16x8*>(&qkt[t * 136 + 64 + ch * 8]);
    *reinterpret_cast<bf16x8*>(Kb + (size_t)(t0 + t) * DK_ + ch * 8) = k8;
  }
}

// ---------------------------------------------------------------------------
// Kernel 5: flash attention + residual.
// grid 1024 blocks: b = bid&7 (XCD-pinned), cs = (bid>>3)&1 (channel half),
// t0 = (bid>>4)*64.  256 threads = 4 waves; wave w: q-rows [t0+16w,+16) for
// QK^T/softmax, channels [cs*256+64w,+64) for PV.  2 blocks resident/CU.
// Per 64-s tile:
//   kf <- k_lds[par] (ds_read, swizzled)  ->  QK^T (8 MFMA)
//   stage K(i+1) DMA -> k_lds[par^1] ; ISSUE_V(i) (asm, 8 loads, regs)
//   softmax (lane-local rows), defer-rescale, P -> p_lds[par]
//   WAIT vmcnt(0)  [K-DMA + V resident; robust to any scratch/spill ops]
//   BAR (lgkmcnt0 + s_barrier)
//   rescale (rare) ; PV (32 MFMA, setprio)
// Register budget: ~130 VGPR + 64 AGPR (o_acc) -> no spills at 2 waves/SIMD
// (R6/R7 lesson: spills corrupt counted-vmcnt discipline -> use vmcnt(0)).
// ---------------------------------------------------------------------------
__global__ __launch_bounds__(256, 2)
void flash_kernel(const unsigned short* __restrict__ Q,
                  const unsigned short* __restrict__ Kk,
                  const unsigned short* __restrict__ V,
                  const float* __restrict__ x, float* __restrict__ out) {
  __shared__ __align__(16) unsigned short k_lds[2][64 * 64];  // 2 x 8KB
  __shared__ __align__(16) unsigned short p_lds[2][64 * 64];  // 2 x 8KB
  __shared__ __align__(16) float scale_lds[2][4][16];
  __shared__ __align__(16) float l_lds[64];
  __shared__ unsigned flags_lds[2];

  const int tid = threadIdx.x;
  const int w = tid >> 6;
  const int lane = tid & 63;
  const int col = lane & 15;
  const int g = lane >> 4;
  const int bid = blockIdx.x;
  const int b = bid & 7;                 // batch == XCD slot
  const int cs = (bid >> 3) & 1;         // channel half
  const int t0 = (bid >> 4) * 64;
  const int trow0 = t0 + w * 16;

  const unsigned short* Qb = Q + (size_t)b * T_ * DK_;
  const unsigned short* Kb = Kk + (size_t)b * T_ * DK_;
  const unsigned short* Vb = V + (size_t)b * C_ * T_;

  // K tile stage: linear LDS dest (wave-uniform base + lane*16), swizzle
  // folded into the per-lane SOURCE address (rule: both-sides-or-neither).
  auto stageK = [&](int par, int s0) {
#pragma unroll
    for (int n = 0; n < 2; ++n) {
      int o = n * 4096 + tid * 16;          // linear LDS byte offset
      int s = o >> 7;                       // s row (128B rows)
      int z = (o & 127) ^ ((s & 7) << 4);   // pre-swizzled source byte
      const char* src = (const char*)Kb + (size_t)(s0 + s) * 128 + z;
      __builtin_amdgcn_global_load_lds(
          (const __attribute__((address_space(1))) unsigned int*)src,
          (__attribute__((address_space(3))) unsigned int*)((char*)k_lds[par] + o),
          16, 0, 0);
    }
  };

  // Q B-fragments (col = q row); pinned so their wait lands here.
  bf16x8 qf0, qf1;
  {
    const unsigned short* qrow = Qb + (size_t)(trow0 + col) * DK_ + g * 8;
    qf0 = *reinterpret_cast<const bf16x8*>(qrow);
    qf1 = *reinterpret_cast<const bf16x8*>(qrow + 32);
    asm volatile("" : "+v"(qf0), "+v"(qf1));
  }

  // V: SGPR base + 4 voffsets (channel rows), imm 0/64 for the two k-steps
  const unsigned long long vbase = rfl64(Vb + (size_t)(cs * 256 + w * 64) * T_);
  unsigned vo0 = (16 * 0 + col) * 8192 + 16 * g;
  unsigned vo1 = (16 * 1 + col) * 8192 + 16 * g;
  unsigned vo2 = (16 * 2 + col) * 8192 + 16 * g;
  unsigned vo3 = (16 * 3 + col) * 8192 + 16 * g;

  bf16x8 vf00, vf10, vf01, vf11, vf02, vf12, vf03, vf13;  // vf[ks][ct]

#define ISSUE_V()                                                          \
  asm volatile(                                                            \
      "global_load_dwordx4 %0, %8, %12\n\t"                                \
      "global_load_dwordx4 %1, %8, %12 offset:64\n\t"                      \
      "global_load_dwordx4 %2, %9, %12\n\t"                                \
      "global_load_dwordx4 %3, %9, %12 offset:64\n\t"                      \
      "global_load_dwordx4 %4, %10, %12\n\t"                               \
      "global_load_dwordx4 %5, %10, %12 offset:64\n\t"                     \
      "global_load_dwordx4 %6, %11, %12\n\t"                               \
      "global_load_dwordx4 %7, %11, %12 offset:64\n\t"                     \
      : "=&v"(vf00), "=&v"(vf10), "=&v"(vf01), "=&v"(vf11),                \
        "=&v"(vf02), "=&v"(vf12), "=&v"(vf03), "=&v"(vf13)                 \
      : "v"(vo0), "v"(vo1), "v"(vo2), "v"(vo3), "s"(vbase))

  float m_run = -1e30f, l_run = 0.f;
  f32x4 o_acc[4][4];
#pragma unroll
  for (int qt = 0; qt < 4; ++qt)
#pragma unroll
    for (int ct = 0; ct < 4; ++ct) o_acc[qt][ct] = (f32x4){0.f, 0.f, 0.f, 0.f};

  stageK(0, 0);
  asm volatile("s_waitcnt vmcnt(0)" ::: "memory");
  __syncthreads();  // K(0) staged and visible

  const float RTHR = 10.0f;  // defer-rescale threshold (log2 domain)
  const int prow = w * 16 + col;           // this lane's q row in p_lds
  const int pswz = (prow & 7) << 4;

  for (int it = 0; it < T_ / 64; ++it) {
    const int par = it & 1;
    char* pbase = (char*)p_lds + par * 8192;
    const char* kbl = (const char*)k_lds + par * 8192;

    // ---- kf from LDS (8 x ds_read_b128, swizzled) ----
    bf16x8 kf[2][4];
#pragma unroll
    for (int ks = 0; ks < 2; ++ks)
#pragma unroll
      for (int j = 0; j < 4; ++j)
        kf[ks][j] = *reinterpret_cast<const bf16x8*>(
            kbl + (col + 16 * j) * 128 + ((64 * ks + 16 * g) ^ ((col & 7) << 4)));

    // ---- S^T = K Q^T (8 MFMA); lane (col=q) holds s = 16j+4g+r ----
    f32x4 sacc[4];
#pragma unroll
    for (int j = 0; j < 4; ++j) sacc[j] = (f32x4){0.f, 0.f, 0.f, 0.f};
#pragma unroll
    for (int j = 0; j < 4; ++j)
      sacc[j] = __builtin_amdgcn_mfma_f32_16x16x32_bf16(kf[0][j], qf0, sacc[j], 0, 0, 0);
#pragma unroll
    for (int j = 0; j < 4; ++j)
      sacc[j] = __builtin_amdgcn_mfma_f32_16x16x32_bf16(kf[1][j], qf1, sacc[j], 0, 0, 0);

    // ---- prefetch K(i+1) into parity LDS; issue this iter's V frags ----
    stageK(par ^ 1, 64 * (it + 1));  // overrun on last iter: valid ws mem
    ISSUE_V();

    // ---- per-row max + defer-rescale ----
    float u0 = fmaxf(fmaxf(sacc[0][0], sacc[0][1]), sacc[0][2]);
    float u1 = fmaxf(fmaxf(sacc[0][3], sacc[1][0]), sacc[1][1]);
    float u2 = fmaxf(fmaxf(sacc[1][2], sacc[1][3]), sacc[2][0]);
    float u3 = fmaxf(fmaxf(sacc[2][1], sacc[2][2]), sacc[2][3]);
    float u4 = fmaxf(fmaxf(sacc[3][0], sacc[3][1]), sacc[3][2]);
    float tm = fmaxf(fmaxf(fmaxf(u0, u1), fmaxf(u2, u3)), fmaxf(u4, sacc[3][3]));
    tm = fmaxf(tm, __shfl_xor(tm, 16));
    tm = fmaxf(tm, __shfl_xor(tm, 32));

    int wave_any = __any(tm > m_run + RTHR);
    float sc = 1.0f;
    if (wave_any) {
      float m_new = fmaxf(m_run, tm);
      sc = __builtin_amdgcn_exp2f(m_run - m_new);
      m_run = m_new;
      if (lane < 16) scale_lds[par][w][lane] = sc;
    }
    if (lane == 0)
      ((volatile unsigned char*)&flags_lds[par])[w] = (unsigned char)wave_any;

    // ---- P = exp2(S - m), cvt_pk pack, 4x ds_write_b64; l update ----
    float rs = 0.f;
    char* prow_base = pbase + prow * 128;
#pragma unroll
    for (int j = 0; j < 4; ++j) {
      float p0 = __builtin_amdgcn_exp2f(sacc[j][0] - m_run);
      float p1 = __builtin_amdgcn_exp2f(sacc[j][1] - m_run);
      float p2 = __builtin_amdgcn_exp2f(sacc[j][2] - m_run);
      float p3 = __builtin_amdgcn_exp2f(sacc[j][3] - m_run);
      rs += (p0 + p1) + (p2 + p3);
      uint2 pk2 = {cvt_pk_bf16(p0, p1), cvt_pk_bf16(p2, p3)};
      *reinterpret_cast<uint2*>(prow_base + (((16 * j + 4 * g) * 2) ^ pswz)) = pk2;
    }
    rs += __shfl_xor(rs, 16);
    rs += __shfl_xor(rs, 32);
    l_run = l_run * sc + rs;

    WAIT_VM0();  // K(i+1) DMA + V(i) resident (count-free => spill-robust)
    BAR_LDS();   // P/scales/flags[par] + k_lds[par^1] visible to all waves

    // ---- o_acc rescale (rare; wave-uniform per qt) ----
    unsigned fl = flags_lds[par];
    if (fl) {
#pragma unroll
      for (int qt = 0; qt < 4; ++qt)
        if ((fl >> (8 * qt)) & 0xffu) {
          f32x4 s4 = *reinterpret_cast<const f32x4*>(&scale_lds[par][qt][4 * g]);
#pragma unroll
          for (int ct = 0; ct < 4; ++ct) o_acc[qt][ct] *= s4;
        }
    }

    // ---- PV: o_acc[qt][ct] += P[16qt..+16] x V[cs*256+64w+16ct..+16] ----
    __builtin_amdgcn_s_setprio(1);
#pragma unroll
    for (int qt = 0; qt < 4; ++qt) {
      int row = 16 * qt + col;
      const char* pr = pbase + row * 128;
      int swz = (row & 7) << 4;
      bf16x8 pa0 = *reinterpret_cast<const bf16x8*>(pr + ((16 * g) ^ swz));
      bf16x8 pa1 = *reinterpret_cast<const bf16x8*>(pr + ((64 + 16 * g) ^ swz));
      o_acc[qt][0] = __builtin_amdgcn_mfma_f32_16x16x32_bf16(pa0, vf00, o_acc[qt][0], 0, 0, 0);
      o_acc[qt][1] = __builtin_amdgcn_mfma_f32_16x16x32_bf16(pa0, vf01, o_acc[qt][1], 0, 0, 0);
      o_acc[qt][2] = __builtin_amdgcn_mfma_f32_16x16x32_bf16(pa0, vf02, o_acc[qt][2], 0, 0, 0);
      o_acc[qt][3] = __builtin_amdgcn_mfma_f32_16x16x32_bf16(pa0, vf03, o_acc[qt][3], 0, 0, 0);
      o_acc[qt][0] = __builtin_amdgcn_mfma_f32_16x16x32_bf16(pa1, vf10, o_acc[qt][0], 0, 0, 0);
      o_acc[qt][1] = __builtin_amdgcn_mfma_f32_16x16x32_bf16(pa1, vf11, o_acc[qt][1], 0, 0, 0);
      o_acc[qt][2] = __builtin_amdgcn_mfma_f32_16x16x32_bf16(pa1, vf12, o_acc[qt][2], 0, 0, 0);
      o_acc[qt][3] = __builtin_amdgcn_mfma_f32_16x16x32_bf16(pa1, vf13, o_acc[qt][3], 0, 0, 0);
    }
    __builtin_amdgcn_s_setprio(0);

    vo0 += 128; vo1 += 128; vo2 += 128; vo3 += 128;  // next s tile
  }

  asm volatile("s_waitcnt vmcnt(0)" ::: "memory");  // drain overrun K DMA

  // ---- epilogue: share l, direct coalesced f32x4 stores + residual ----
  if (lane < 16) l_lds[w * 16 + lane] = l_run;
  BAR_LDS();

  const float* xb = x + (size_t)b * C_ * T_;
  float* ob = out + (size_t)b * C_ * T_;
  const int cb = cs * 256 + w * 64;
#pragma unroll
  for (int qt = 0; qt < 4; ++qt) {
    f32x4 l4 = *reinterpret_cast<const f32x4*>(&l_lds[16 * qt + 4 * g]);
    f32x4 linv;
#pragma unroll
    for (int r = 0; r < 4; ++r) linv[r] = 1.f / l4[r];
#pragma unroll
    for (int ct = 0; ct < 4; ++ct) {
      size_t idx = (size_t)(cb + 16 * ct + col) * T_ + t0 + 16 * qt + 4 * g;
      f32x4 xv = *reinterpret_cast<const f32x4*>(xb + idx);
      f32x4 o = o_acc[qt][ct];
#pragma unroll
      for (int r = 0; r < 4; ++r) o[r] = o[r] * linv[r] + xv[r];
      *reinterpret_cast<f32x4*>(ob + idx) = o;
    }
  }
#undef ISSUE_V
}

// ---------------------------------------------------------------------------
extern "C" void kernel_launch(void* const* d_in, const int* in_sizes, int n_in,
                              void* d_out, int out_size, void* d_ws, size_t ws_size,
                              hipStream_t stream) {
  const float* x  = (const float*)d_in[0];
  const float* Wq = (const float*)d_in[1];
  const float* Wk = (const float*)d_in[2];
  const float* Wv = (const float*)d_in[3];
  const float* bv = (const float*)d_in[4];
  const float* u  = (const float*)d_in[5];
  float* out = (float*)d_out;

  char* ws = (char*)d_ws;
  float* sig = (float*)ws;
  unsigned short* Q  = (unsigned short*)(ws + 1024);
  unsigned short* Kk = (unsigned short*)(ws + 1024 + (size_t)4 * 1024 * 1024);
  unsigned short* V  = (unsigned short*)(ws + 1024 + (size_t)8 * 1024 * 1024);
  unsigned short* xT = (unsigned short*)(ws + 1024 + (size_t)40 * 1024 * 1024);
  unsigned short* Wc = (unsigned short*)(ws + 1024 + (size_t)72 * 1024 * 1024);

  sigma_kernel<<<1, 512, 0, stream>>>(Wv, u, sig);
  castw_kernel<<<640, 128, 0, stream>>>(Wq, Wk, Wv, sig, Wc);
  castt_kernel<<<dim3(T_ / 64, C_ / 64, B_), 256, 0, stream>>>(x, xT);
  proj_kernel<<<256, 512, 0, stream>>>(Wc, xT, bv, Q, Kk, V);
  flash_kernel<<<1024, 256, 0, stream>>>(Q, Kk, V, x, out);
}

// Round 9
// 384.532 us; speedup vs baseline: 1.0815x; 1.0309x over previous
//
#include <hip/hip_runtime.h>

// ---------------------------------------------------------------------------
// SelfAttention (B=8, C=512, T=4096, DK=64):
//   sigma = spectral norm of Wv (1 power iter); val = (Wv x)/sigma + bv
//   q = Wq x, k = Wk x; attn = softmax(q^T k / 8); out = val @ attn^T + x
// Pipeline:
//   sigma  -> inv_sigma
//   castw  -> Wc[640][512] bf16 = [Wq*log2e/8 ; Wk ; Wv/sigma]
//   castt  -> xT[b][t][c] bf16 (LDS transpose)
//   proj   -> unified MFMA GEMM: Q[t][d], K[t][d], V[c][t] (+bv)
//   flash  -> flash attention: 4-wave blocks (64q x 128ch), 4 blocks/CU
//             (R8 post-mortem: co-resident blocks hide each other's serial
//             chain 1:1 -> maximize block concurrency), K tile in LDS (DMA,
//             parity), V in regs, ONE vmcnt(0)+lgkm barrier per tile
// ---------------------------------------------------------------------------

#define B_  8
#define C_  512
#define T_  4096
#define DK_ 64

typedef __bf16 bf16x8 __attribute__((ext_vector_type(8)));
typedef float  f32x4  __attribute__((ext_vector_type(4)));

static __device__ __forceinline__ unsigned short f2bf(float f) {
  unsigned u = __float_as_uint(f);
  u += 0x7fffu + ((u >> 16) & 1u);
  return (unsigned short)(u >> 16);
}

static __device__ __forceinline__ unsigned cvt_pk_bf16(float a, float b) {
  unsigned r;  // r.lo = bf16(a), r.hi = bf16(b), RNE
  asm("v_cvt_pk_bf16_f32 %0, %1, %2" : "=v"(r) : "v"(a), "v"(b));
  return r;
}

static __device__ __forceinline__ unsigned long long rfl64(const void* p) {
  unsigned long long a = (unsigned long long)p;
  unsigned lo = __builtin_amdgcn_readfirstlane((unsigned)a);
  unsigned hi = __builtin_amdgcn_readfirstlane((unsigned)(a >> 32));
  return ((unsigned long long)hi << 32) | lo;
}

// raw barrier: LDS-visibility wait + barrier
#define BAR_LDS() asm volatile("s_waitcnt lgkmcnt(0)\ns_barrier" ::: "memory")
// full VMEM drain + scheduling fence (robust to compiler-inserted scratch ops)
#define WAIT_VM0() do { asm volatile("s_waitcnt vmcnt(0)" ::: "memory"); \
                        __builtin_amdgcn_sched_barrier(0); } while (0)

// ---------------------------------------------------------------------------
// Kernel 1: spectral norm -> inv_sigma
// ---------------------------------------------------------------------------
__global__ void sigma_kernel(const float* __restrict__ Wv,
                             const float* __restrict__ u,
                             float* __restrict__ sig) {
  __shared__ float red[512];
  __shared__ float vsh[512];
  __shared__ float snorm;
  int tid = threadIdx.x;  // 512 threads

  vsh[tid] = u[tid];
  __syncthreads();
  float acc = 0.f;
  for (int j = 0; j < 512; ++j) acc += Wv[(size_t)j * 512 + tid] * vsh[j];
  red[tid] = acc * acc;
  __syncthreads();
  for (int s = 256; s >= 1; s >>= 1) {
    if (tid < s) red[tid] += red[tid + s];
    __syncthreads();
  }
  if (tid == 0) snorm = sqrtf(red[0]) + 1e-12f;
  __syncthreads();
  float v = acc / snorm;
  __syncthreads();
  vsh[tid] = v;
  __syncthreads();
  float wacc = 0.f;
  for (int c = 0; c < 512; ++c) wacc += Wv[(size_t)tid * 512 + c] * vsh[c];
  red[tid] = wacc * wacc;
  __syncthreads();
  for (int s = 256; s >= 1; s >>= 1) {
    if (tid < s) red[tid] += red[tid + s];
    __syncthreads();
  }
  if (tid == 0) {
    float ww = red[0];
    float sigma = ww / (sqrtf(ww) + 1e-12f);
    sig[0] = 1.f / sigma;
  }
}

// ---------------------------------------------------------------------------
// Kernel 2: stack + scale weights to bf16: Wc[640][512]
// ---------------------------------------------------------------------------
__global__ __launch_bounds__(128)
void castw_kernel(const float* __restrict__ Wq, const float* __restrict__ Wk,
                  const float* __restrict__ Wv, const float* __restrict__ sig,
                  unsigned short* __restrict__ Wc) {
  int row = blockIdx.x;
  int c = threadIdx.x * 4;
  const float* src;
  float s;
  if (row < 64) {
    src = Wq + (size_t)row * 512;
    s = 1.4426950408889634f / 8.0f;
  } else if (row < 128) {
    src = Wk + (size_t)(row - 64) * 512;
    s = 1.0f;
  } else {
    src = Wv + (size_t)(row - 128) * 512;
    s = sig[0];
  }
  float4 v = *reinterpret_cast<const float4*>(src + c);
  ushort4 o;
  o.x = f2bf(v.x * s);
  o.y = f2bf(v.y * s);
  o.z = f2bf(v.z * s);
  o.w = f2bf(v.w * s);
  *reinterpret_cast<ushort4*>(Wc + (size_t)row * 512 + c) = o;
}

// ---------------------------------------------------------------------------
// Kernel 3: transpose-cast x[b][c][t] f32 -> xT[b][t][c] bf16.
// ---------------------------------------------------------------------------
__global__ __launch_bounds__(256)
void castt_kernel(const float* __restrict__ x, unsigned short* __restrict__ xT) {
  __shared__ __align__(16) unsigned short ldsT[64][72];  // [t][c], +8 pad
  int tid = threadIdx.x;
  int t0 = blockIdx.x * 64, c0 = blockIdx.y * 64, b = blockIdx.z;
  const float* xb = x + ((size_t)b * C_ + c0) * T_ + t0;
#pragma unroll
  for (int k2 = 0; k2 < 4; ++k2) {
    int idx = k2 * 256 + tid;
    int c = idx >> 4, t4 = (idx & 15) * 4;
    float4 v = *reinterpret_cast<const float4*>(xb + (size_t)c * T_ + t4);
    ldsT[t4 + 0][c] = f2bf(v.x);
    ldsT[t4 + 1][c] = f2bf(v.y);
    ldsT[t4 + 2][c] = f2bf(v.z);
    ldsT[t4 + 3][c] = f2bf(v.w);
  }
  __syncthreads();
  unsigned short* xTb = xT + ((size_t)b * T_ + t0) * C_ + c0;
#pragma unroll
  for (int k2 = 0; k2 < 2; ++k2) {
    int idx = k2 * 256 + tid;
    int t = idx >> 3, ch = idx & 7;
    bf16x8 v = *reinterpret_cast<const bf16x8*>(&ldsT[t][ch * 8]);
    *reinterpret_cast<bf16x8*>(xTb + (size_t)t * C_ + ch * 8) = v;
  }
}

// ---------------------------------------------------------------------------
// Kernel 4: unified projection GEMM (bf16 MFMA).  (unchanged, verified)
// ---------------------------------------------------------------------------
__global__ __launch_bounds__(512, 2)
void proj_kernel(const unsigned short* __restrict__ Wc,
                 const unsigned short* __restrict__ xT,
                 const float* __restrict__ bv,
                 unsigned short* __restrict__ Q,
                 unsigned short* __restrict__ Kk,
                 unsigned short* __restrict__ V) {
  __shared__ __align__(16) char smem[98304];  // 96KB: x 2x8KB | W 2x40KB
  const int tid = threadIdx.x;
  const int w = tid >> 6;
  const int lane = tid & 63;
  const int col = lane & 15;
  const int g = lane >> 4;
  const int b = blockIdx.x & 7;
  const int t0 = (blockIdx.x >> 3) * 128;

  const unsigned short* xTb = xT + ((size_t)b * T_ + t0) * C_;

  auto stageX = [&](int bsel, int kc) {
    int off = w * 1024 + lane * 16;
    int tl = off >> 6;
    int cb = off & 63;
    const unsigned short* src = xTb + (size_t)tl * C_ + kc + cb / 2;
    __builtin_amdgcn_global_load_lds(
        (const __attribute__((address_space(1))) unsigned int*)src,
        (__attribute__((address_space(3))) unsigned int*)(smem + bsel * 8192 + off),
        16, 0, 0);
  };
  auto stageW = [&](int bsel, int kc) {
#pragma unroll
    for (int i = 0; i < 5; ++i) {
      int off = i * 8192 + w * 1024 + lane * 16;
      int o = off >> 6;
      int cb = off & 63;
      const unsigned short* src = Wc + (size_t)o * 512 + kc + cb / 2;
      __builtin_amdgcn_global_load_lds(
          (const __attribute__((address_space(1))) unsigned int*)src,
          (__attribute__((address_space(3))) unsigned int*)(smem + 16384 + bsel * 40960 + off),
          16, 0, 0);
    }
  };

  f32x4 acc[5][8];
#pragma unroll
  for (int of = 0; of < 5; ++of)
#pragma unroll
    for (int j = 0; j < 8; ++j) acc[of][j] = (f32x4){0.f, 0.f, 0.f, 0.f};

  stageX(0, 0);
  stageW(0, 0);
  __syncthreads();
  int cur = 0;

  for (int ks = 0; ks < 16; ++ks) {
    int kc = ks * 32;
    if (ks < 15) {
      stageX(cur ^ 1, kc + 32);
      stageW(cur ^ 1, kc + 32);
    }
    bf16x8 af[5], bfr[8];
#pragma unroll
    for (int of = 0; of < 5; ++of) {
      int o = w * 80 + of * 16 + col;
      af[of] = *reinterpret_cast<const bf16x8*>(smem + 16384 + cur * 40960 + o * 64 + g * 16);
    }
#pragma unroll
    for (int j = 0; j < 8; ++j) {
      int tl = 16 * j + col;
      bfr[j] = *reinterpret_cast<const bf16x8*>(smem + cur * 8192 + tl * 64 + g * 16);
    }
#pragma unroll
    for (int of = 0; of < 5; ++of)
#pragma unroll
      for (int j = 0; j < 8; ++j)
        acc[of][j] = __builtin_amdgcn_mfma_f32_16x16x32_bf16(af[of], bfr[j], acc[of][j], 0, 0, 0);
    __syncthreads();
    cur ^= 1;
  }

  unsigned short* qkt = (unsigned short*)smem;                       // [128][136]
  unsigned short* vt = (unsigned short*)(smem + 34816 + w * 4352);   // [16][136]/wave
  unsigned short* Vb = V + (size_t)b * C_ * T_;

#pragma unroll
  for (int of = 0; of < 5; ++of) {
    int o0 = w * 80 + of * 16;
    if (o0 < 128) {
#pragma unroll
      for (int j = 0; j < 8; ++j)
#pragma unroll
        for (int r = 0; r < 4; ++r)
          qkt[(16 * j + col) * 136 + o0 + g * 4 + r] = f2bf(acc[of][j][r]);
    } else {
      int c0 = o0 - 128;
      float bvr[4];
#pragma unroll
      for (int r = 0; r < 4; ++r) bvr[r] = bv[c0 + g * 4 + r];
#pragma unroll
      for (int j = 0; j < 8; ++j)
#pragma unroll
        for (int r = 0; r < 4; ++r)
          vt[(g * 4 + r) * 136 + 16 * j + col] = f2bf(acc[of][j][r] + bvr[r]);
#pragma unroll
      for (int p = 0; p < 4; ++p) {
        int o_r = p * 4 + g;
        bf16x8 v8 = *reinterpret_cast<const bf16x8*>((char*)vt + o_r * 272 + col * 16);
        *reinterpret_cast<bf16x8*>(Vb + (size_t)(c0 + o_r) * T_ + t0 + col * 8) = v8;
      }
    }
  }
  __syncthreads();
  unsigned short* Qb = Q + (size_t)b * T_ * DK_;
  unsigned short* Kb = Kk + (size_t)b * T_ * DK_;
#pragma unroll
  for (int k2 = 0; k2 < 2; ++k2) {
    int idx = k2 * 512 + tid;
    int t = idx >> 3, ch = idx & 7;
    bf16x8 q8 = *reinterpret_cast<const bf16x8*>(&qkt[t * 136 + ch * 8]);
    *reinterpret_cast<bf16x8*>(Qb + (size_t)(t0 + t) * DK_ + ch * 8) = q8;
    bf16x8 k8 = *reinterpret_cast<const bf16x8*>(&qkt[t * 136 + 64 + ch * 8]);
    *reinterpret_cast<bf16x8*>(Kb + (size_t)(t0 + t) * DK_ + ch * 8) = k8;
  }
}

// ---------------------------------------------------------------------------
// Kernel 5: flash attention + residual.
// grid 2048 blocks: b = bid&7 (XCD-pinned), cs = (bid>>3)&3 (channel quarter),
// t0 = (bid>>5)*64.  256 threads = 4 waves; wave w: q-rows [t0+16w,+16) for
// QK^T/softmax, channels [cs*128+32w,+32) for PV.  Target 4 blocks/CU
// (16 waves) -> co-resident blocks hide each other's serial chain (R8
// post-mortem: overlap gave 1.8x per-iter; regs 144>128 capped it at 2).
// Budget: o_acc 32 AGPR + ~70 VGPR <= 128 total; LDS 33KB x4 = 132 <= 160.
// Per 64-s tile (sync protocol identical to verified R8):
//   kf <- k_lds[par] (ds_read, swizzled) -> QK^T (8 MFMA, setprio)
//   ISSUE_V(i) (asm, 4 loads) ; stage K(i+1) DMA -> k_lds[par^1]
//   softmax (lane-local rows), defer-rescale, P -> p_lds[par]
//   WAIT vmcnt(0) ; BAR(lgkm)
//   rescale (rare) ; PV (16 MFMA, setprio)
// ---------------------------------------------------------------------------
__global__ __launch_bounds__(256, 4)
void flash_kernel(const unsigned short* __restrict__ Q,
                  const unsigned short* __restrict__ Kk,
                  const unsigned short* __restrict__ V,
                  const float* __restrict__ x, float* __restrict__ out) {
  __shared__ __align__(16) unsigned short k_lds[2][64 * 64];  // 2 x 8KB
  __shared__ __align__(16) unsigned short p_lds[2][64 * 64];  // 2 x 8KB
  __shared__ __align__(16) float scale_lds[2][4][16];
  __shared__ __align__(16) float l_lds[64];
  __shared__ unsigned flags_lds[2];

  const int tid = threadIdx.x;
  const int w = tid >> 6;
  const int lane = tid & 63;
  const int col = lane & 15;
  const int g = lane >> 4;
  const int bid = blockIdx.x;
  const int b = bid & 7;                 // batch == XCD slot
  const int cs = (bid >> 3) & 3;         // channel quarter
  const int t0 = (bid >> 5) * 64;
  const int trow0 = t0 + w * 16;

  const unsigned short* Qb = Q + (size_t)b * T_ * DK_;
  const unsigned short* Kb = Kk + (size_t)b * T_ * DK_;
  const unsigned short* Vb = V + (size_t)b * C_ * T_;

  // K tile stage: linear LDS dest (wave-uniform base + lane*16), swizzle
  // folded into the per-lane SOURCE address (rule: both-sides-or-neither).
  auto stageK = [&](int par, int s0) {
#pragma unroll
    for (int n = 0; n < 2; ++n) {
      int o = n * 4096 + tid * 16;          // linear LDS byte offset
      int s = o >> 7;                       // s row (128B rows)
      int z = (o & 127) ^ ((s & 7) << 4);   // pre-swizzled source byte
      const char* src = (const char*)Kb + (size_t)(s0 + s) * 128 + z;
      __builtin_amdgcn_global_load_lds(
          (const __attribute__((address_space(1))) unsigned int*)src,
          (__attribute__((address_space(3))) unsigned int*)((char*)k_lds[par] + o),
          16, 0, 0);
    }
  };

  // Q B-fragments (col = q row); pinned so their wait lands here.
  bf16x8 qf0, qf1;
  {
    const unsigned short* qrow = Qb + (size_t)(trow0 + col) * DK_ + g * 8;
    qf0 = *reinterpret_cast<const bf16x8*>(qrow);
    qf1 = *reinterpret_cast<const bf16x8*>(qrow + 32);
    asm volatile("" : "+v"(qf0), "+v"(qf1));
  }

  // V: SGPR base + 2 voffsets (channel rows), imm 0/64 for the two k-steps
  const unsigned long long vbase = rfl64(Vb + (size_t)(cs * 128 + w * 32) * T_);
  unsigned vo0 = (16 * 0 + col) * 8192 + 16 * g;
  unsigned vo1 = (16 * 1 + col) * 8192 + 16 * g;

  bf16x8 vf00, vf10, vf01, vf11;  // vf[ks][ct]

#define ISSUE_V()                                                          \
  asm volatile(                                                            \
      "global_load_dwordx4 %0, %4, %6\n\t"                                 \
      "global_load_dwordx4 %1, %4, %6 offset:64\n\t"                       \
      "global_load_dwordx4 %2, %5, %6\n\t"                                 \
      "global_load_dwordx4 %3, %5, %6 offset:64\n\t"                       \
      : "=&v"(vf00), "=&v"(vf10), "=&v"(vf01), "=&v"(vf11)                 \
      : "v"(vo0), "v"(vo1), "s"(vbase))

  float m_run = -1e30f, l_run = 0.f;
  f32x4 o_acc[4][2];
#pragma unroll
  for (int qt = 0; qt < 4; ++qt)
#pragma unroll
    for (int ct = 0; ct < 2; ++ct) o_acc[qt][ct] = (f32x4){0.f, 0.f, 0.f, 0.f};

  stageK(0, 0);
  asm volatile("s_waitcnt vmcnt(0)" ::: "memory");
  __syncthreads();  // K(0) staged and visible

  const float RTHR = 10.0f;  // defer-rescale threshold (log2 domain)
  const int prow = w * 16 + col;           // this lane's q row in p_lds
  const int pswz = (prow & 7) << 4;

  for (int it = 0; it < T_ / 64; ++it) {
    const int par = it & 1;
    char* pbase = (char*)p_lds + par * 8192;
    const char* kbl = (const char*)k_lds + par * 8192;

    // ---- kf from LDS (8 x ds_read_b128, swizzled) ----
    bf16x8 kf[2][4];
#pragma unroll
    for (int ks = 0; ks < 2; ++ks)
#pragma unroll
      for (int j = 0; j < 4; ++j)
        kf[ks][j] = *reinterpret_cast<const bf16x8*>(
            kbl + (col + 16 * j) * 128 + ((64 * ks + 16 * g) ^ ((col & 7) << 4)));

    // ---- S^T = K Q^T (8 MFMA); lane (col=q) holds s = 16j+4g+r ----
    f32x4 sacc[4];
#pragma unroll
    for (int j = 0; j < 4; ++j) sacc[j] = (f32x4){0.f, 0.f, 0.f, 0.f};
    __builtin_amdgcn_s_setprio(1);
#pragma unroll
    for (int j = 0; j < 4; ++j)
      sacc[j] = __builtin_amdgcn_mfma_f32_16x16x32_bf16(kf[0][j], qf0, sacc[j], 0, 0, 0);
#pragma unroll
    for (int j = 0; j < 4; ++j)
      sacc[j] = __builtin_amdgcn_mfma_f32_16x16x32_bf16(kf[1][j], qf1, sacc[j], 0, 0, 0);
    __builtin_amdgcn_s_setprio(0);

    // ---- issue this iter's V frags (longest latency slack first),
    //      then prefetch K(i+1) into parity LDS ----
    ISSUE_V();
    stageK(par ^ 1, 64 * (it + 1));  // overrun on last iter: valid ws mem

    // ---- per-row max + defer-rescale ----
    float u0 = fmaxf(fmaxf(sacc[0][0], sacc[0][1]), sacc[0][2]);
    float u1 = fmaxf(fmaxf(sacc[0][3], sacc[1][0]), sacc[1][1]);
    float u2 = fmaxf(fmaxf(sacc[1][2], sacc[1][3]), sacc[2][0]);
    float u3 = fmaxf(fmaxf(sacc[2][1], sacc[2][2]), sacc[2][3]);
    float u4 = fmaxf(fmaxf(sacc[3][0], sacc[3][1]), sacc[3][2]);
    float tm = fmaxf(fmaxf(fmaxf(u0, u1), fmaxf(u2, u3)), fmaxf(u4, sacc[3][3]));
    tm = fmaxf(tm, __shfl_xor(tm, 16));
    tm = fmaxf(tm, __shfl_xor(tm, 32));

    int wave_any = __any(tm > m_run + RTHR);
    float sc = 1.0f;
    if (wave_any) {
      float m_new = fmaxf(m_run, tm);
      sc = __builtin_amdgcn_exp2f(m_run - m_new);
      m_run = m_new;
      if (lane < 16) scale_lds[par][w][lane] = sc;
    }
    if (lane == 0)
      ((volatile unsigned char*)&flags_lds[par])[w] = (unsigned char)wave_any;

    // ---- P = exp2(S - m), cvt_pk pack, 4x ds_write_b64; l update ----
    float rs = 0.f;
    char* prow_base = pbase + prow * 128;
#pragma unroll
    for (int j = 0; j < 4; ++j) {
      float p0 = __builtin_amdgcn_exp2f(sacc[j][0] - m_run);
      float p1 = __builtin_amdgcn_exp2f(sacc[j][1] - m_run);
      float p2 = __builtin_amdgcn_exp2f(sacc[j][2] - m_run);
      float p3 = __builtin_amdgcn_exp2f(sacc[j][3] - m_run);
      rs += (p0 + p1) + (p2 + p3);
      uint2 pk2 = {cvt_pk_bf16(p0, p1), cvt_pk_bf16(p2, p3)};
      *reinterpret_cast<uint2*>(prow_base + (((16 * j + 4 * g) * 2) ^ pswz)) = pk2;
    }
    rs += __shfl_xor(rs, 16);
    rs += __shfl_xor(rs, 32);
    l_run = l_run * sc + rs;

    WAIT_VM0();  // V(i) + K(i+1) DMA resident (count-free => spill-robust)
    BAR_LDS();   // P/scales/flags[par] + k_lds[par^1] visible to all waves

    // ---- o_acc rescale (rare; wave-uniform per qt) ----
    unsigned fl = flags_lds[par];
    if (fl) {
#pragma unroll
      for (int qt = 0; qt < 4; ++qt)
        if ((fl >> (8 * qt)) & 0xffu) {
          f32x4 s4 = *reinterpret_cast<const f32x4*>(&scale_lds[par][qt][4 * g]);
#pragma unroll
          for (int ct = 0; ct < 2; ++ct) o_acc[qt][ct] *= s4;
        }
    }

    // ---- PV: o_acc[qt][ct] += P[16qt..+16] x V[cs*128+32w+16ct..+16] ----
    __builtin_amdgcn_s_setprio(1);
#pragma unroll
    for (int qt = 0; qt < 4; ++qt) {
      int row = 16 * qt + col;
      const char* pr = pbase + row * 128;
      int swz = (row & 7) << 4;
      bf16x8 pa0 = *reinterpret_cast<const bf16x8*>(pr + ((16 * g) ^ swz));
      bf16x8 pa1 = *reinterpret_cast<const bf16x8*>(pr + ((64 + 16 * g) ^ swz));
      o_acc[qt][0] = __builtin_amdgcn_mfma_f32_16x16x32_bf16(pa0, vf00, o_acc[qt][0], 0, 0, 0);
      o_acc[qt][1] = __builtin_amdgcn_mfma_f32_16x16x32_bf16(pa0, vf01, o_acc[qt][1], 0, 0, 0);
      o_acc[qt][0] = __builtin_amdgcn_mfma_f32_16x16x32_bf16(pa1, vf10, o_acc[qt][0], 0, 0, 0);
      o_acc[qt][1] = __builtin_amdgcn_mfma_f32_16x16x32_bf16(pa1, vf11, o_acc[qt][1], 0, 0, 0);
    }
    __builtin_amdgcn_s_setprio(0);

    vo0 += 128;
    vo1 += 128;  // next s tile
  }

  asm volatile("s_waitcnt vmcnt(0)" ::: "memory");  // drain overrun K DMA

  // ---- epilogue: share l, direct coalesced f32x4 stores + residual ----
  if (lane < 16) l_lds[w * 16 + lane] = l_run;
  BAR_LDS();

  const float* xb = x + (size_t)b * C_ * T_;
  float* ob = out + (size_t)b * C_ * T_;
  const int cb = cs * 128 + w * 32;
#pragma unroll
  for (int qt = 0; qt < 4; ++qt) {
    f32x4 l4 = *reinterpret_cast<const f32x4*>(&l_lds[16 * qt + 4 * g]);
    f32x4 linv;
#pragma unroll
    for (int r = 0; r < 4; ++r) linv[r] = 1.f / l4[r];
#pragma unroll
    for (int ct = 0; ct < 2; ++ct) {
      size_t idx = (size_t)(cb + 16 * ct + col) * T_ + t0 + 16 * qt + 4 * g;
      f32x4 xv = *reinterpret_cast<const f32x4*>(xb + idx);
      f32x4 o = o_acc[qt][ct];
#pragma unroll
      for (int r = 0; r < 4; ++r) o[r] = o[r] * linv[r] + xv[r];
      *reinterpret_cast<f32x4*>(ob + idx) = o;
    }
  }
#undef ISSUE_V
}

// ---------------------------------------------------------------------------
extern "C" void kernel_launch(void* const* d_in, const int* in_sizes, int n_in,
                              void* d_out, int out_size, void* d_ws, size_t ws_size,
                              hipStream_t stream) {
  const float* x  = (const float*)d_in[0];
  const float* Wq = (const float*)d_in[1];
  const float* Wk = (const float*)d_in[2];
  const float* Wv = (const float*)d_in[3];
  const float* bv = (const float*)d_in[4];
  const float* u  = (const float*)d_in[5];
  float* out = (float*)d_out;

  char* ws = (char*)d_ws;
  float* sig = (float*)ws;
  unsigned short* Q  = (unsigned short*)(ws + 1024);
  unsigned short* Kk = (unsigned short*)(ws + 1024 + (size_t)4 * 1024 * 1024);
  unsigned short* V  = (unsigned short*)(ws + 1024 + (size_t)8 * 1024 * 1024);
  unsigned short* xT = (unsigned short*)(ws + 1024 + (size_t)40 * 1024 * 1024);
  unsigned short* Wc = (unsigned short*)(ws + 1024 + (size_t)72 * 1024 * 1024);

  sigma_kernel<<<1, 512, 0, stream>>>(Wv, u, sig);
  castw_kernel<<<640, 128, 0, stream>>>(Wq, Wk, Wv, sig, Wc);
  castt_kernel<<<dim3(T_ / 64, C_ / 64, B_), 256, 0, stream>>>(x, xT);
  proj_kernel<<<256, 512, 0, stream>>>(Wc, xT, bv, Q, Kk, V);
  flash_kernel<<<2048, 256, 0, stream>>>(Q, Kk, V, x, out);
}